// Round 1
// baseline (659.538 us; speedup 1.0000x reference)
//
#include <hip/hip_runtime.h>
#include <cstdint>
#include <cstddef>

// Problem constants (from reference)
#define NN 50000
#define NE 800000
static constexpr int IN_F = 512;
static constexpr int HID  = 256;
static constexpr int OUTF = 128;

// ---------------- graph preprocessing ----------------

__global__ void k_degree(const int* __restrict__ src, const int* __restrict__ dst,
                         int* __restrict__ deg_out, int* __restrict__ deg_in, int E) {
  int e = blockIdx.x * blockDim.x + threadIdx.x;
  if (e < E) {
    atomicAdd(&deg_out[src[e]], 1);
    atomicAdd(&deg_in[dst[e]], 1);
  }
}

__global__ void k_norm(const int* __restrict__ deg_out, const int* __restrict__ deg_in,
                       float* __restrict__ norm_src, float* __restrict__ norm_dst, int N) {
  int i = blockIdx.x * blockDim.x + threadIdx.x;
  if (i < N) {
    int dO = deg_out[i]; if (dO < 1) dO = 1;
    int dI = deg_in[i];  if (dI < 1) dI = 1;
    norm_src[i] = rsqrtf((float)dO);
    norm_dst[i] = rsqrtf((float)dI);
  }
}

// scan step 1: per-512-chunk exclusive scan of deg_in, chunk totals to bsums
__global__ void k_scan1(const int* __restrict__ deg_in, int* __restrict__ excl,
                        int* __restrict__ bsums, int N) {
  __shared__ int s[512];
  int t = threadIdx.x;
  int g = blockIdx.x * 512 + t;
  int v = (g < N) ? deg_in[g] : 0;
  s[t] = v;
  __syncthreads();
  for (int off = 1; off < 512; off <<= 1) {
    int add = (t >= off) ? s[t - off] : 0;
    __syncthreads();
    s[t] += add;
    __syncthreads();
  }
  if (g < N) excl[g] = s[t] - v;
  if (t == 511) bsums[blockIdx.x] = s[511];
}

// scan step 2: single-block exclusive scan of chunk totals (nb <= 128)
__global__ void k_scan2(int* __restrict__ bsums, int nb) {
  __shared__ int s[128];
  int t = threadIdx.x;
  int v = (t < nb) ? bsums[t] : 0;
  s[t] = v;
  __syncthreads();
  for (int off = 1; off < 128; off <<= 1) {
    int add = (t >= off) ? s[t - off] : 0;
    __syncthreads();
    s[t] += add;
    __syncthreads();
  }
  if (t < nb) bsums[t] = s[t] - v;  // exclusive
}

// scan step 3: add chunk offsets -> global row offsets; write sentinel
__global__ void k_scan3(int* __restrict__ row_off, const int* __restrict__ bsums,
                        int N, int E) {
  int g = blockIdx.x * blockDim.x + threadIdx.x;
  if (g < N) row_off[g] += bsums[g >> 9];
  if (g == 0) row_off[N] = E;
}

// counting-sort edges by dst: sorted src node per CSR slot
__global__ void k_fill(const int* __restrict__ src, const int* __restrict__ dst,
                       const int* __restrict__ row_off, int* __restrict__ cursor,
                       int* __restrict__ ssrc, int E) {
  int e = blockIdx.x * blockDim.x + threadIdx.x;
  if (e < E) {
    int d = dst[e];
    int pos = atomicAdd(&cursor[d], 1);
    ssrc[row_off[d] + pos] = src[e];
  }
}

// ---------------- fp32 tiled GEMM with fused row scale ----------------
// C[M][N] = (A[m][:] * rowscale[m]) @ B,  A: MxK row-major, B: KxN row-major.
// BM=BN=64, BK=32, 256 threads, 4x4 per thread.
__launch_bounds__(256)
__global__ void k_gemm_rowscale(const float* __restrict__ A, const float* __restrict__ B,
                                const float* __restrict__ rowscale, float* __restrict__ C,
                                int M, int N, int K) {
  constexpr int BM = 64, BN = 64, BK = 32;
  __shared__ float As[BK][BM + 4];  // k-major; +4 keeps float4 rows 16B-aligned
  __shared__ float Bs[BK][BN + 4];
  const int tid = threadIdx.x;
  const int bm = blockIdx.x * BM;
  const int bn = blockIdx.y * BN;
  const int tx = tid & 15;   // col group
  const int ty = tid >> 4;   // row group (0..15)
  float acc[4][4] = {};

  for (int k0 = 0; k0 < K; k0 += BK) {
    // A tile: 64 rows x 32 k = 512 float4, 2 per thread; transpose to k-major with scale
#pragma unroll
    for (int l = 0; l < 2; ++l) {
      int f = tid + l * 256;
      int m = f >> 3, kq = f & 7;
      int gm = bm + m;
      float4 v = make_float4(0.f, 0.f, 0.f, 0.f);
      float sc = 0.f;
      if (gm < M) {
        v = *(const float4*)(A + (size_t)gm * K + k0 + kq * 4);
        sc = rowscale[gm];
      }
      As[kq * 4 + 0][m] = v.x * sc;
      As[kq * 4 + 1][m] = v.y * sc;
      As[kq * 4 + 2][m] = v.z * sc;
      As[kq * 4 + 3][m] = v.w * sc;
    }
    // B tile: 32 k x 64 n = 512 float4, 2 per thread, direct layout
#pragma unroll
    for (int l = 0; l < 2; ++l) {
      int f = tid + l * 256;
      int kk = f >> 4, nq = f & 15;
      *(float4*)&Bs[kk][nq * 4] = *(const float4*)(B + (size_t)(k0 + kk) * N + bn + nq * 4);
    }
    __syncthreads();
#pragma unroll
    for (int kk = 0; kk < BK; ++kk) {
      float4 a4 = *(const float4*)&As[kk][ty * 4];
      float4 b4 = *(const float4*)&Bs[kk][tx * 4];
      float a[4] = {a4.x, a4.y, a4.z, a4.w};
      float b[4] = {b4.x, b4.y, b4.z, b4.w};
#pragma unroll
      for (int i = 0; i < 4; ++i)
#pragma unroll
        for (int j = 0; j < 4; ++j)
          acc[i][j] = fmaf(a[i], b[j], acc[i][j]);
    }
    __syncthreads();
  }

#pragma unroll
  for (int i = 0; i < 4; ++i) {
    int gm = bm + ty * 4 + i;
    if (gm < M) {
      float4 o = make_float4(acc[i][0], acc[i][1], acc[i][2], acc[i][3]);
      *(float4*)(C + (size_t)gm * N + bn + tx * 4) = o;
    }
  }
}

// ---------------- CSR aggregation (one wave per dst node) ----------------
// out[n] = act( sum_{e in CSR(n)} Hpre[ssrc[e]] * norm_dst[n] + bias )
template <int F, bool RELU>
__launch_bounds__(256)
__global__ void k_agg(const float* __restrict__ Hpre, const int* __restrict__ row_off,
                      const int* __restrict__ ssrc, const float* __restrict__ norm_dst,
                      const float* __restrict__ bias, float* __restrict__ out, int N) {
  int wid = (blockIdx.x * 256 + threadIdx.x) >> 6;
  int lane = threadIdx.x & 63;
  if (wid >= N) return;
  int beg = row_off[wid], end = row_off[wid + 1];

  if constexpr (F == 256) {
    float4 acc = make_float4(0.f, 0.f, 0.f, 0.f);
    int nxt = (beg < end) ? ssrc[beg] : 0;
    for (int e = beg; e < end; ++e) {
      int s = nxt;
      if (e + 1 < end) nxt = ssrc[e + 1];
      const float4 v = *(const float4*)(Hpre + (size_t)s * 256 + lane * 4);
      acc.x += v.x; acc.y += v.y; acc.z += v.z; acc.w += v.w;
    }
    float nd = norm_dst[wid];
    const float4 bb = *(const float4*)(bias + lane * 4);
    float4 o = make_float4(fmaf(acc.x, nd, bb.x), fmaf(acc.y, nd, bb.y),
                           fmaf(acc.z, nd, bb.z), fmaf(acc.w, nd, bb.w));
    if (RELU) {
      o.x = fmaxf(o.x, 0.f); o.y = fmaxf(o.y, 0.f);
      o.z = fmaxf(o.z, 0.f); o.w = fmaxf(o.w, 0.f);
    }
    *(float4*)(out + (size_t)wid * 256 + lane * 4) = o;
  } else {  // F == 128: float2 per lane
    float2 acc = make_float2(0.f, 0.f);
    int nxt = (beg < end) ? ssrc[beg] : 0;
    for (int e = beg; e < end; ++e) {
      int s = nxt;
      if (e + 1 < end) nxt = ssrc[e + 1];
      const float2 v = *(const float2*)(Hpre + (size_t)s * 128 + lane * 2);
      acc.x += v.x; acc.y += v.y;
    }
    float nd = norm_dst[wid];
    const float2 bb = *(const float2*)(bias + lane * 2);
    float2 o = make_float2(fmaf(acc.x, nd, bb.x), fmaf(acc.y, nd, bb.y));
    if (RELU) { o.x = fmaxf(o.x, 0.f); o.y = fmaxf(o.y, 0.f); }
    *(float2*)(out + (size_t)wid * 128 + lane * 2) = o;
  }
}

// ---------------- launch ----------------

extern "C" void kernel_launch(void* const* d_in, const int* in_sizes, int n_in,
                              void* d_out, int out_size, void* d_ws, size_t ws_size,
                              hipStream_t stream) {
  const float* X  = (const float*)d_in[0];
  const float* W1 = (const float*)d_in[1];
  const float* b1 = (const float*)d_in[2];
  const float* W2 = (const float*)d_in[3];
  const float* b2 = (const float*)d_in[4];
  const int* src  = (const int*)d_in[5];
  const int* dst  = (const int*)d_in[6];
  float* out = (float*)d_out;

  char* p = (char*)d_ws;
  auto alloc = [&](size_t bytes) -> char* {
    char* r = p;
    p += (bytes + 255) & ~(size_t)255;
    return r;
  };
  float* H1pre  = (float*)alloc((size_t)NN * HID * 4);   // X@W1 pre-agg
  float* H1post = (float*)alloc((size_t)NN * HID * 4);   // relu layer-1 out
  float* H2pre  = H1pre;                                  // reuse (H1pre dead after agg1)
  int* deg_out  = (int*)alloc((size_t)NN * 4);
  int* deg_in   = (int*)alloc((size_t)NN * 4);
  int* cursor   = (int*)alloc((size_t)NN * 4);
  int* row_off  = (int*)alloc((size_t)(NN + 1) * 4);
  int* bsums    = (int*)alloc(512);
  float* nsrc   = (float*)alloc((size_t)NN * 4);
  float* ndst   = (float*)alloc((size_t)NN * 4);
  int* ssrc     = (int*)alloc((size_t)NE * 4);

  // zero the atomic accumulators (deg_out..cursor are contiguous in ws)
  hipMemsetAsync(deg_out, 0, (size_t)((char*)row_off - (char*)deg_out), stream);

  k_degree<<<(NE + 255) / 256, 256, 0, stream>>>(src, dst, deg_out, deg_in, NE);
  k_norm<<<(NN + 255) / 256, 256, 0, stream>>>(deg_out, deg_in, nsrc, ndst, NN);

  int nb = (NN + 511) / 512;  // 98
  k_scan1<<<nb, 512, 0, stream>>>(deg_in, row_off, bsums, NN);
  k_scan2<<<1, 128, 0, stream>>>(bsums, nb);
  k_scan3<<<(NN + 255) / 256, 256, 0, stream>>>(row_off, bsums, NN, NE);
  k_fill<<<(NE + 255) / 256, 256, 0, stream>>>(src, dst, row_off, cursor, ssrc, NE);

  // layer 1: H1pre = (X * nsrc) @ W1 ; H1post = relu(agg * ndst + b1)
  dim3 g1((NN + 63) / 64, HID / 64);
  k_gemm_rowscale<<<g1, 256, 0, stream>>>(X, W1, nsrc, H1pre, NN, HID, IN_F);
  k_agg<256, true><<<(NN * 64 + 255) / 256, 256, 0, stream>>>(
      H1pre, row_off, ssrc, ndst, b1, H1post, NN);

  // layer 2: H2pre = (H1post * nsrc) @ W2 ; out = agg * ndst + b2
  dim3 g2((NN + 63) / 64, OUTF / 64);
  k_gemm_rowscale<<<g2, 256, 0, stream>>>(H1post, W2, nsrc, H2pre, NN, OUTF, HID);
  k_agg<128, false><<<(NN * 64 + 255) / 256, 256, 0, stream>>>(
      H2pre, row_off, ssrc, ndst, b2, out, NN);
}